// Round 18
// baseline (2042.330 us; speedup 1.0000x reference)
//
#include <hip/hip_runtime.h>
#include <math.h>

// ---------------------------------------------------------------------------
// sLSTM block, round 17: scan h-broadcast collapsed to ONE ds_read_b128 per
// lane + 3 row_ror DPP allgather stages (LDS-pipe instr/CU/step 56 -> ~34,
// the measured stagger source). ROR direction resolved by a one-time runtime
// probe that permutes the weight slot order. Everything else = r16.
// Workspace: same as r16 (~49.6 MB).
// ---------------------------------------------------------------------------

#define D_MODEL 1024
#define NHEAD   8
#define DPH     128
#define DFF     2048
#define BATCH   8
#define SEQ     2048
#define NROWS   (BATCH * SEQ)   // 16384
#define CHUNK_L 256             // scan steps per launch (8 launches)
#define TGRP    16              // scan steps per staged group (unrolled)
#define NGRP    (CHUNK_L / TGRP)
#define ROWCH   4096            // FFN rows per chunk (4 chunks)
#define LN_EPS  1e-5f

typedef __attribute__((ext_vector_type(8))) short short8;
typedef __attribute__((ext_vector_type(4))) short short4v;
typedef __attribute__((ext_vector_type(4))) float f32x4;
typedef __attribute__((ext_vector_type(2))) _Float16 h2f;

#if __has_builtin(__builtin_amdgcn_fdot2)
#define DOT2(a, b, c) __builtin_amdgcn_fdot2((a), (b), (c), false)
#else
__device__ __forceinline__ float DOT2(h2f a, h2f b, float c) {
  return c + (float)a.x * (float)b.x + (float)a.y * (float)b.y;
}
#endif

#if __has_builtin(__builtin_amdgcn_rcpf)
#define FRCP(x) __builtin_amdgcn_rcpf(x)
#else
#define FRCP(x) (1.0f / (x))
#endif

__device__ __forceinline__ h2f pc(int u) {
  union { int i; h2f h; } c; c.i = u; return c.h;
}

__device__ __forceinline__ float qxor1(float v) {
#if __has_builtin(__builtin_amdgcn_update_dpp)
  union { float f; int i; } u; u.f = v;
  u.i = __builtin_amdgcn_update_dpp(u.i, u.i, 0xB1, 0xf, 0xf, true);
  return u.f;
#else
  return __shfl_xor(v, 1, 64);
#endif
}
__device__ __forceinline__ float qxor2(float v) {
#if __has_builtin(__builtin_amdgcn_update_dpp)
  union { float f; int i; } u; u.f = v;
  u.i = __builtin_amdgcn_update_dpp(u.i, u.i, 0x4E, 0xf, 0xf, true);
  return u.f;
#else
  return __shfl_xor(v, 2, 64);
#endif
}

template <int CTRL>
__device__ __forceinline__ int dppror(int v) {
#if __has_builtin(__builtin_amdgcn_update_dpp)
  return __builtin_amdgcn_update_dpp(v, v, CTRL, 0xf, 0xf, true);
#else
  return v;   // unused in fallback path
#endif
}

// async global->LDS, 16B per lane; lds_base must be WAVE-UNIFORM
__device__ __forceinline__ void gll16(const void* src, void* lds_base, int lane) {
#if __has_builtin(__builtin_amdgcn_global_load_lds)
  __builtin_amdgcn_global_load_lds(
      (const __attribute__((address_space(1))) unsigned int*)src,
      (__attribute__((address_space(3))) unsigned int*)lds_base, 16, 0, 0);
#else
  *(float4*)((char*)lds_base + lane * 16) = *(const float4*)src;
#endif
}

__device__ __forceinline__ float gelu_exact(float x) {
  return 0.5f * x * (1.0f + erff(x * 0.70710678118654752440f));
}

__device__ __forceinline__ unsigned short f2bf(float f) {
  union { float f; unsigned int u; } v; v.f = f;
  unsigned int r = v.u + 0x7fffu + ((v.u >> 16) & 1u);
  return (unsigned short)(r >> 16);
}

// tile-image offset for element (r, k) inside a [128][64] bf16 tile
__device__ __forceinline__ int img_off(int r, int k) {
  return r * 64 + ((((k >> 3) & 7) ^ (r & 7)) << 3) + (k & 7);
}

// sLSTM gate update: division-free + single-exp max-trick; returns raw h
__device__ __forceinline__ float gate_step(float iv, float fv, float zraw, float oraw,
                                           float& c, float& nrm, float& m) {
  const float zv = 1.0f - 2.0f * FRCP(__expf(2.0f * zraw) + 1.0f);
  const float ov = FRCP(1.0f + __expf(-oraw));
  const float lf = fminf(fv, 0.0f) - __logf(1.0f + __expf(-fabsf(fv)));
  const float ft = lf + m;
  const float mn = fmaxf(ft, iv);
  const float e  = __expf(fminf(ft, iv) - mn);
  const float is = (iv < ft) ? e : 1.0f;
  const float fs = (iv < ft) ? 1.0f : e;
  c = fs * c + is * zv;
  nrm = fs * nrm + is;
  m = mn;
  return ov * c * FRCP(nrm);
}

// --------------------- per-row LN stats (mu, rstd) --------------------------
__global__ __launch_bounds__(256) void ln_stats_kernel(
    const float* __restrict__ in, float* __restrict__ mu_out,
    float* __restrict__ rs_out) {
  const int row = blockIdx.x, tid = threadIdx.x;
  const float4 v = ((const float4*)(in + (size_t)row * D_MODEL))[tid];
  float s  = v.x + v.y + v.z + v.w;
  float s2 = v.x*v.x + v.y*v.y + v.z*v.z + v.w*v.w;
  #pragma unroll
  for (int m = 1; m < 64; m <<= 1) { s += __shfl_xor(s, m, 64); s2 += __shfl_xor(s2, m, 64); }
  __shared__ float sa[4], sb[4];
  if ((tid & 63) == 0) { sa[tid >> 6] = s; sb[tid >> 6] = s2; }
  __syncthreads();
  if (tid == 0) {
    const float S  = sa[0] + sa[1] + sa[2] + sa[3];
    const float S2 = sb[0] + sb[1] + sb[2] + sb[3];
    const float mu = S * (1.0f / D_MODEL);
    const float var = S2 * (1.0f / D_MODEL) - mu * mu;
    mu_out[row] = mu;
    rs_out[row] = rsqrtf(var + LN_EPS);
  }
}

// ---- weight convert: [K][N] f32 -> bf16 tile images -------------------------
__global__ __launch_bounds__(256) void cvt_w(
    const float* __restrict__ src, short* __restrict__ dst, int K, int N) {
  __shared__ float tile[64][68];
  const int n0 = blockIdx.x * 64;
  const int k0 = blockIdx.y * 64;
  const int tid = threadIdx.x;
  #pragma unroll
  for (int i = 0; i < 16; ++i) {
    const int e = i * 256 + tid;
    const int kk = e >> 6, nn = e & 63;
    tile[kk][nn] = src[(size_t)(k0 + kk) * N + n0 + nn];
  }
  __syncthreads();
  const int ktiles = K >> 6;
  #pragma unroll
  for (int i = 0; i < 2; ++i) {
    const int e = i * 256 + tid;
    const int nn = e >> 3, kc = (e & 7) * 8;
    short8 s;
    #pragma unroll
    for (int j = 0; j < 8; ++j) s[j] = (short)f2bf(tile[kc + j][nn]);
    const int n = n0 + nn;
    const size_t base = ((size_t)(n >> 7) * ktiles + (k0 >> 6)) * 8192;
    *(short8*)(dst + base + img_off(n & 127, kc)) = s;
  }
}

// ---- hh_w [128][512] f32 -> packed f16 pairs hh2[k2][512] -------------------
__global__ __launch_bounds__(256) void cvt_hh(
    const float* __restrict__ hhw, h2f* __restrict__ hh2) {
  const int idx = blockIdx.x * 256 + threadIdx.x;
  const int k2 = idx >> 9, j = idx & 511;
  h2f v;
  v.x = (_Float16)hhw[(size_t)(2 * k2) * 512 + j];
  v.y = (_Float16)hhw[(size_t)(2 * k2 + 1) * 512 + j];
  hh2[idx] = v;
}

// ------ cvt_x: LN1(x) chunk rows as bf16 tile images -------------------------
__global__ __launch_bounds__(256) void cvt_x(
    const float* __restrict__ x, const float* __restrict__ mu1,
    const float* __restrict__ rs1, const float* __restrict__ ln1w,
    const float* __restrict__ ln1b, short* __restrict__ xb, int l0) {
  const int rowm = blockIdx.x, tid = threadIdx.x;
  const int l = l0 + (rowm >> 3), b = rowm & 7;
  const int grow = b * SEQ + l;
  const float4 v = ((const float4*)(x + (size_t)grow * D_MODEL))[tid];
  const float mu = mu1[grow], rs = rs1[grow];
  const float4 w4 = ((const float4*)ln1w)[tid];
  const float4 b4 = ((const float4*)ln1b)[tid];
  short4v s;
  s[0] = (short)f2bf((v.x - mu) * rs * w4.x + b4.x);
  s[1] = (short)f2bf((v.y - mu) * rs * w4.y + b4.y);
  s[2] = (short)f2bf((v.z - mu) * rs * w4.z + b4.z);
  s[3] = (short)f2bf((v.w - mu) * rs * w4.w + b4.w);
  const int k = tid * 4;
  const int h = k >> 7, khead = k & 127;
  const size_t base = (((size_t)(rowm >> 7) * 8 + h) * 2 + (khead >> 6)) * 8192;
  *(short4v*)(xb + base + img_off(rowm & 127, khead & 63)) = s;
}

// ---------------- proj (bf16 MFMA, gll16) + bias, bank-rotated store ---------
__global__ __launch_bounds__(256) void proj_mfma(
    const short* __restrict__ xb, const short* __restrict__ ihwb,
    const float* __restrict__ ihb, float* __restrict__ proj) {
  __shared__ short As[128 * 64];
  __shared__ short Bs[128 * 64];
  const int tid = threadIdx.x;
  const int mb = blockIdx.x;
  const int qb = blockIdx.y;
  const int h  = blockIdx.z;
  const int lane = tid & 63;
  const int w = tid >> 6;
  const int wr = w >> 1, wc = w & 1;
  const short* at = xb + ((size_t)(mb * 8 + h) * 2) * 8192;
  const short* bt = ihwb + ((size_t)(h * 8 + qb * 2)) * 8192;
  f32x4 acc[4][4];
  #pragma unroll
  for (int i = 0; i < 4; ++i)
    #pragma unroll
    for (int j = 0; j < 4; ++j) acc[i][j] = (f32x4)0.0f;
  #pragma unroll
  for (int kb = 0; kb < 2; ++kb) {
    #pragma unroll
    for (int i = 0; i < 4; ++i) {
      const int off = i * 2048 + w * 512;
      gll16(at + (size_t)kb * 8192 + off + lane * 8, As + off, lane);
      gll16(bt + (size_t)kb * 8192 + off + lane * 8, Bs + off, lane);
    }
    __syncthreads();
    #pragma unroll
    for (int ks = 0; ks < 2; ++ks) {
      short8 af[4], bf[4];
      #pragma unroll
      for (int mf = 0; mf < 4; ++mf) {
        const int row = wr * 64 + mf * 16 + (lane & 15);
        const int c8 = ks * 4 + (lane >> 4);
        af[mf] = *(const short8*)&As[row * 64 + ((c8 ^ (row & 7)) << 3)];
      }
      #pragma unroll
      for (int nf = 0; nf < 4; ++nf) {
        const int row = wc * 64 + nf * 16 + (lane & 15);
        const int c8 = ks * 4 + (lane >> 4);
        bf[nf] = *(const short8*)&Bs[row * 64 + ((c8 ^ (row & 7)) << 3)];
      }
      #pragma unroll
      for (int mf = 0; mf < 4; ++mf)
        #pragma unroll
        for (int nf = 0; nf < 4; ++nf)
          acc[mf][nf] = __builtin_amdgcn_mfma_f32_16x16x32_bf16(af[mf], bf[nf], acc[mf][nf], 0, 0, 0);
    }
    __syncthreads();
  }
  #pragma unroll
  for (int nf = 0; nf < 4; ++nf) {
    const int col = wc * 64 + nf * 16 + (lane & 15);
    const float bias = ihb[h * 512 + qb * 128 + col];
    const int pos = qb * 128 + ((col + 8 * qb) & 127);
    #pragma unroll
    for (int mf = 0; mf < 4; ++mf) {
      const int rbase = mb * 128 + wr * 64 + mf * 16 + ((lane >> 4) << 2);
      #pragma unroll
      for (int rr = 0; rr < 4; ++rr)
        proj[((size_t)(rbase + rr) * NHEAD + h) * 512 + pos] = acc[mf][nf][rr] + bias;
    }
  }
}

// ------------------------------- sLSTM scan --------------------------------
// h-read: ONE ds_read_b128 per lane (own 16B chunk c0 of quarter q) + 3
// row_ror DPP allgather stages. ROR direction resolved once via probe ->
// weight slot permutation. Butterfly/gates/staging unchanged from r16.
__global__ __launch_bounds__(512, 1) void scan_chunk(
    const float* __restrict__ proj, const h2f* __restrict__ hh2,
    float* __restrict__ state, float* __restrict__ hout, int l0) {
  const int bh = blockIdx.x, b = bh >> 3, h = bh & 7;
  const int tid = threadIdx.x;
  const int l = tid & 63, w = tid >> 6;
  const int q = l & 3, p = l >> 2;
  const int c0 = p & 3;                            // own chunk within quarter
  const int ch = 16 * w + p;
  const int pvoff = q * 128 + ((ch + 8 * q) & 127);
  __shared__ __align__(16) _Float16 h16[2][128];
  __shared__ __align__(16) float pbuf[2][TGRP][512];
  __shared__ __align__(16) float hstage[2][TGRP][128];

  // ROR direction probe: does row_ror:4 deliver from lane l+4 or l-4?
#if __has_builtin(__builtin_amdgcn_update_dpp)
  const int pr = __builtin_amdgcn_update_dpp(l, l, 0x124, 0xf, 0xf, true);
  const bool plus = ((pr & 15) == ((l + 4) & 15));
#else
  const bool plus = true;
#endif

  // weights, slot-ordered: slot k pairs with chunk (c0 +/- k) & 3 of quarter q
  h2f w2[4][16];
  #pragma unroll
  for (int k = 0; k < 4; ++k) {
    const int ck = (c0 + (plus ? k : ((4 - k) & 3))) & 3;
    #pragma unroll
    for (int j = 0; j < 4; ++j)
      #pragma unroll
      for (int e = 0; e < 4; ++e)
        w2[j][k * 4 + e] = hh2[(size_t)(16 * q + 4 * ck + e) * 512 + j * 128 + ch];
  }

  float c, nrm, m;
  if (l0 == 0) {
    c = 0.0f; nrm = 0.0f; m = -1e30f;
    if (q == 0) h16[0][ch] = (_Float16)0.0f;
  } else {
    c   = state[bh * 128 + ch];
    nrm = state[8192  + bh * 128 + ch];
    m   = state[16384 + bh * 128 + ch];
    if (q == 0) h16[0][ch] = (_Float16)state[24576 + bh * 128 + ch];
  }

  const float* pbase = proj + (size_t)bh * 512;

  #define STAGE(NB, GR)                                                        \
    {                                                                          \
      _Pragma("unroll")                                                        \
      for (int i = 0; i < 4; ++i) {                                            \
        const int hr = i * 8 + w;                                              \
        const float* src = pbase + (size_t)((GR) * TGRP + (hr >> 1)) * 32768   \
                           + (hr & 1) * 256 + l * 4;                           \
        float* dst = &pbuf[NB][0][0] + hr * 256;                               \
        gll16(src, dst, l);                                                    \
      }                                                                        \
    }

  // DOT4: consume one gathered 16B register (4 h2f pairs) against slot K
  #define DOT4(RG, K)                                                          \
    {                                                                          \
      const h2f h0 = pc(RG.x), h1 = pc(RG.y), h2_ = pc(RG.z), h3 = pc(RG.w);   \
      pa0 = DOT2(h0, w2[0][4*(K)+0], pa0); pa0 = DOT2(h1, w2[0][4*(K)+1], pa0);\
      pa0 = DOT2(h2_, w2[0][4*(K)+2], pa0); pa0 = DOT2(h3, w2[0][4*(K)+3], pa0);\
      pa1 = DOT2(h0, w2[1][4*(K)+0], pa1); pa1 = DOT2(h1, w2[1][4*(K)+1], pa1);\
      pa1 = DOT2(h2_, w2[1][4*(K)+2], pa1); pa1 = DOT2(h3, w2[1][4*(K)+3], pa1);\
      pa2 = DOT2(h0, w2[2][4*(K)+0], pa2); pa2 = DOT2(h1, w2[2][4*(K)+1], pa2);\
      pa2 = DOT2(h2_, w2[2][4*(K)+2], pa2); pa2 = DOT2(h3, w2[2][4*(K)+3], pa2);\
      pa3 = DOT2(h0, w2[3][4*(K)+0], pa3); pa3 = DOT2(h1, w2[3][4*(K)+1], pa3);\
      pa3 = DOT2(h2_, w2[3][4*(K)+2], pa3); pa3 = DOT2(h3, w2[3][4*(K)+3], pa3);\
    }

  STAGE(0, 0)
  asm volatile("s_waitcnt vmcnt(0)" ::: "memory");
  __syncthreads();

  float hv = 0.0f;
  for (int grp = 0; grp < NGRP; ++grp) {
    const int gb = grp & 1;
    if (grp + 1 < NGRP) STAGE(gb ^ 1, grp + 1)
    #pragma unroll
    for (int tl = 0; tl < TGRP; ++tl) {
      const int cur = tl & 1;
      // one b128: own chunk of quarter q (<=2-way bank aliasing = free)
      const int4 own = *(const int4*)&h16[cur][q * 32 + c0 * 8];
      // allgather the other 3 chunks via row_ror (VALU DPP, no LDS)
      int4 g1, g2, g3;
#if __has_builtin(__builtin_amdgcn_update_dpp)
      g1.x = dppror<0x124>(own.x); g1.y = dppror<0x124>(own.y);
      g1.z = dppror<0x124>(own.z); g1.w = dppror<0x124>(own.w);
      g2.x = dppror<0x128>(own.x); g2.y = dppror<0x128>(own.y);
      g2.z = dppror<0x128>(own.z); g2.w = dppror<0x128>(own.w);
      g3.x = dppror<0x12C>(own.x); g3.y = dppror<0x12C>(own.y);
      g3.z = dppror<0x12C>(own.z); g3.w = dppror<0x12C>(own.w);
#else
      {
        const int base = l & ~15;
        const int s1 = base | ((l + 4) & 15);
        const int s2 = base | ((l + 8) & 15);
        const int s3 = base | ((l + 12) & 15);
        g1.x = __shfl(own.x, s1, 64); g1.y = __shfl(own.y, s1, 64);
        g1.z = __shfl(own.z, s1, 64); g1.w = __shfl(own.w, s1, 64);
        g2.x = __shfl(own.x, s2, 64); g2.y = __shfl(own.y, s2, 64);
        g2.z = __shfl(own.z, s2, 64); g2.w = __shfl(own.w, s2, 64);
        g3.x = __shfl(own.x, s3, 64); g3.y = __shfl(own.y, s3, 64);
        g3.z = __shfl(own.z, s3, 64); g3.w = __shfl(own.w, s3, 64);
      }
#endif
      float pa0 = 0.0f, pa1 = 0.0f, pa2 = 0.0f, pa3 = 0.0f;
      DOT4(own, 0) DOT4(g1, 1) DOT4(g2, 2) DOT4(g3, 3)
      // proj term (conflict-free rotated read); lane q owns column q*128+ch
      const float pv = pbuf[gb][tl][pvoff];
      pa0 += (q == 0) ? pv : 0.0f;
      pa1 += (q == 1) ? pv : 0.0f;
      pa2 += (q == 2) ? pv : 0.0f;
      pa3 += (q == 3) ? pv : 0.0f;
      // quad butterfly: elementwise sum over the 4 K-quarters (VALU DPP)
      pa0 += qxor1(pa0); pa1 += qxor1(pa1); pa2 += qxor1(pa2); pa3 += qxor1(pa3);
      pa0 += qxor2(pa0); pa1 += qxor2(pa1); pa2 += qxor2(pa2); pa3 += qxor2(pa3);
      hv = gate_step(pa0, pa1, pa2, pa3, c, nrm, m);
      if (q == 0) {
        h16[cur ^ 1][ch] = (_Float16)hv;
        hstage[gb][tl][ch] = hv;
      }
      __syncthreads();                               // the one barrier per step
    }
    {
      const int s = tid >> 5, c8 = (tid & 31) << 2;
      const float4 v0 = *(const float4*)&hstage[gb][s][c8];
      *(float4*)(hout + ((size_t)(b * SEQ + l0 + grp * TGRP + s)) * D_MODEL
                 + h * DPH + c8) = v0;
    }
  }

  if (q == 0) {
    state[bh * 128 + ch]          = c;
    state[8192  + bh * 128 + ch]  = nrm;
    state[16384 + bh * 128 + ch]  = m;
    state[24576 + bh * 128 + ch]  = hv;
  }
  #undef STAGE
  #undef DOT4
}

// ---------- post: y = headLN(h) + x in place on d_out ; LN2 row stats -------
__global__ __launch_bounds__(256) void post_kernel(
    float* __restrict__ yio, const float* __restrict__ x,
    const float* __restrict__ hnw, const float* __restrict__ hnb,
    float* __restrict__ mu2, float* __restrict__ rs2) {
  const int row = blockIdx.x, tid = threadIdx.x;
  const float4 hv = ((const float4*)(yio + (size_t)row * D_MODEL))[tid];
  float s  = hv.x + hv.y + hv.z + hv.w;
  float s2 = hv.x*hv.x + hv.y*hv.y + hv.z*hv.z + hv.w*hv.w;
  #pragma unroll
  for (int mm = 1; mm < 32; mm <<= 1) {
    s  += __shfl_xor(s,  mm, 32);
    s2 += __shfl_xor(s2, mm, 32);
  }
  const float mu = s * (1.0f / DPH);
  const float var = s2 * (1.0f / DPH) - mu * mu;
  const float rstd = rsqrtf(var + LN_EPS);
  const int dq = tid & 31;
  const float4 w4 = ((const float4*)hnw)[dq];
  const float4 b4 = ((const float4*)hnb)[dq];
  const float4 xv = ((const float4*)(x + (size_t)row * D_MODEL))[tid];
  float4 yv;
  yv.x = (hv.x - mu) * rstd * w4.x + b4.x + xv.x;
  yv.y = (hv.y - mu) * rstd * w4.y + b4.y + xv.y;
  yv.z = (hv.z - mu) * rstd * w4.z + b4.z + xv.z;
  yv.w = (hv.w - mu) * rstd * w4.w + b4.w + xv.w;
  ((float4*)(yio + (size_t)row * D_MODEL))[tid] = yv;
  float t1 = yv.x + yv.y + yv.z + yv.w;
  float t2 = yv.x*yv.x + yv.y*yv.y + yv.z*yv.z + yv.w*yv.w;
  #pragma unroll
  for (int mm = 1; mm < 64; mm <<= 1) {
    t1 += __shfl_xor(t1, mm, 64);
    t2 += __shfl_xor(t2, mm, 64);
  }
  __shared__ float sa[4], sb[4];
  if ((tid & 63) == 0) { sa[tid >> 6] = t1; sb[tid >> 6] = t2; }
  __syncthreads();
  if (tid == 0) {
    const float S  = sa[0] + sa[1] + sa[2] + sa[3];
    const float S2 = sb[0] + sb[1] + sb[2] + sb[3];
    const float m2 = S * (1.0f / D_MODEL);
    const float v2 = S2 * (1.0f / D_MODEL) - m2 * m2;
    mu2[row] = m2;
    rs2[row] = rsqrtf(v2 + LN_EPS);
  }
}

// ------ cvt_z: z = LN2(y) as bf16 tile images (per ROWCH chunk) -------------
__global__ __launch_bounds__(256) void cvt_z(
    const float* __restrict__ y, const float* __restrict__ mu2,
    const float* __restrict__ rs2, const float* __restrict__ ln2w,
    const float* __restrict__ ln2b, short* __restrict__ zb, int row0) {
  const int lrow = blockIdx.x, tid = threadIdx.x;
  const int grow = row0 + lrow;
  const float4 v = ((const float4*)(y + (size_t)grow * D_MODEL))[tid];
  const float mu = mu2[grow], rs = rs2[grow];
  const float4 w4 = ((const float4*)ln2w)[tid];
  const float4 b4 = ((const float4*)ln2b)[tid];
  short4v s;
  s[0] = (short)f2bf((v.x - mu) * rs * w4.x + b4.x);
  s[1] = (short)f2bf((v.y - mu) * rs * w4.y + b4.y);
  s[2] = (short)f2bf((v.z - mu) * rs * w4.z + b4.z);
  s[3] = (short)f2bf((v.w - mu) * rs * w4.w + b4.w);
  const int k = tid * 4;
  const size_t base = ((size_t)(lrow >> 7) * 16 + (k >> 6)) * 8192;
  *(short4v*)(zb + base + img_off(lrow & 127, k & 63)) = s;
}

// ------------------------------ FF1 (bf16 MFMA, gll16) ----------------------
__global__ __launch_bounds__(256) void ff1_gemm(
    const short* __restrict__ zb, const short* __restrict__ w1b,
    const float* __restrict__ b1, short* __restrict__ g) {
  __shared__ short As[128 * 64];
  __shared__ short Bs1[128 * 64];
  __shared__ short Bs2[128 * 64];
  const int tid = threadIdx.x;
  const int mb = blockIdx.x;
  const int nb = blockIdx.y;
  const int lane = tid & 63;
  const int w = tid >> 6;
  const int wr = w >> 1, wc = w & 1;
  const short* at = zb + (size_t)mb * 16 * 8192;
  const short* b1t = w1b + (size_t)nb * 16 * 8192;
  const short* b2t = w1b + (size_t)(16 + nb) * 16 * 8192;
  f32x4 acc1[4][4], acc2[4][4];
  #pragma unroll
  for (int i = 0; i < 4; ++i)
    #pragma unroll
    for (int j = 0; j < 4; ++j) { acc1[i][j] = (f32x4)0.0f; acc2[i][j] = (f32x4)0.0f; }
  for (int kb = 0; kb < 16; ++kb) {
    #pragma unroll
    for (int i = 0; i < 4; ++i) {
      const int off = i * 2048 + w * 512;
      gll16(at + (size_t)kb * 8192 + off + lane * 8, As + off, lane);
      gll16(b1t + (size_t)kb * 8192 + off + lane * 8, Bs1 + off, lane);
      gll16(b2t + (size_t)kb * 8192 + off + lane * 8, Bs2 + off, lane);
    }
    __syncthreads();
    #pragma unroll
    for (int ks = 0; ks < 2; ++ks) {
      short8 af[4], b1f[4], b2f[4];
      #pragma unroll
      for (int mf = 0; mf < 4; ++mf) {
        const int row = wr * 64 + mf * 16 + (lane & 15);
        const int c8 = ks * 4 + (lane >> 4);
        af[mf] = *(const short8*)&As[row * 64 + ((c8 ^ (row & 7)) << 3)];
      }
      #pragma unroll
      for (int nf = 0; nf < 4; ++nf) {
        const int row = wc * 64 + nf * 16 + (lane & 15);
        const int c8 = ks * 4 + (lane >> 4);
        const int off = row * 64 + ((c8 ^ (row & 7)) << 3);
        b1f[nf] = *(const short8*)&Bs1[off];
        b2f[nf] = *(const short8*)&Bs2[off];
      }
      #pragma unroll
      for (int mf = 0; mf < 4; ++mf)
        #pragma unroll
        for (int nf = 0; nf < 4; ++nf) {
          acc1[mf][nf] = __builtin_amdgcn_mfma_f32_16x16x32_bf16(af[mf], b1f[nf], acc1[mf][nf], 0, 0, 0);
          acc2[mf][nf] = __builtin_amdgcn_mfma_f32_16x16x32_bf16(af[mf], b2f[nf], acc2[mf][nf], 0, 0, 0);
        }
    }
    __syncthreads();
  }
  #pragma unroll
  for (int nf = 0; nf < 4; ++nf) {
    const int col = nb * 128 + wc * 64 + nf * 16 + (lane & 15);
    const float bx1 = b1[col], bx2 = b1[DFF + col];
    #pragma unroll
    for (int mf = 0; mf < 4; ++mf) {
      const int rloc = wr * 64 + mf * 16 + ((lane >> 4) << 2);
      #pragma unroll
      for (int rr = 0; rr < 4; ++rr) {
        const float x1 = acc1[mf][nf][rr] + bx1;
        const float x2 = acc2[mf][nf][rr] + bx2;
        const int r = rloc + rr;
        const size_t base = ((size_t)mb * 32 + (col >> 6)) * 8192;
        g[base + img_off(r, col & 63)] = (short)f2bf(x1 * gelu_exact(x2));
      }
    }
  }
}

// --------------- FF2 (bf16 MFMA, gll16) + bias + residual, in place ----------
__global__ __launch_bounds__(256) void ff2_gemm(
    const short* __restrict__ g, const short* __restrict__ w2b,
    const float* __restrict__ b2, float* __restrict__ out, int row0) {
  __shared__ short As[128 * 64];
  __shared__ short Bs[128 * 64];
  const int tid = threadIdx.x;
  const int mb = blockIdx.x;
  const int nb = blockIdx.y;
  const int lane = tid & 63;
  const int w = tid >> 6;
  const int wr = w >> 1, wc = w & 1;
  const short* at = g + (size_t)mb * 32 * 8192;
  const short* bt = w2b + (size_t)nb * 32 * 8192;
  f32x4 acc[4][4];
  #pragma unroll
  for (int i = 0; i < 4; ++i)
    #pragma unroll
    for (int j = 0; j < 4; ++j) acc[i][j] = (f32x4)0.0f;
  for (int kb = 0; kb < 32; ++kb) {
    #pragma unroll
    for (int i = 0; i < 4; ++i) {
      const int off = i * 2048 + w * 512;
      gll16(at + (size_t)kb * 8192 + off + lane * 8, As + off, lane);
      gll16(bt + (size_t)kb * 8192 + off + lane * 8, Bs + off, lane);
    }
    __syncthreads();
    #pragma unroll
    for (int ks = 0; ks < 2; ++ks) {
      short8 af[4], bf[4];
      #pragma unroll
      for (int mf = 0; mf < 4; ++mf) {
        const int row = wr * 64 + mf * 16 + (lane & 15);
        const int c8 = ks * 4 + (lane >> 4);
        af[mf] = *(const short8*)&As[row * 64 + ((c8 ^ (row & 7)) << 3)];
      }
      #pragma unroll
      for (int nf = 0; nf < 4; ++nf) {
        const int row = wc * 64 + nf * 16 + (lane & 15);
        const int c8 = ks * 4 + (lane >> 4);
        bf[nf] = *(const short8*)&Bs[row * 64 + ((c8 ^ (row & 7)) << 3)];
      }
      #pragma unroll
      for (int mf = 0; mf < 4; ++mf)
        #pragma unroll
        for (int nf = 0; nf < 4; ++nf)
          acc[mf][nf] = __builtin_amdgcn_mfma_f32_16x16x32_bf16(af[mf], bf[nf], acc[mf][nf], 0, 0, 0);
    }
    __syncthreads();
  }
  #pragma unroll
  for (int nf = 0; nf < 4; ++nf) {
    const int col = nb * 128 + wc * 64 + nf * 16 + (lane & 15);
    const float bias = b2[col];
    #pragma unroll
    for (int mf = 0; mf < 4; ++mf) {
      const int rbase = row0 + mb * 128 + wr * 64 + mf * 16 + ((lane >> 4) << 2);
      #pragma unroll
      for (int rr = 0; rr < 4; ++rr) {
        float* p = out + (size_t)(rbase + rr) * D_MODEL + col;
        *p = acc[mf][nf][rr] + bias + *p;
      }
    }
  }
}

// ------------------------------- launcher -----------------------------------
extern "C" void kernel_launch(void* const* d_in, const int* in_sizes, int n_in,
                              void* d_out, int out_size, void* d_ws, size_t ws_size,
                              hipStream_t stream) {
  const float* x    = (const float*)d_in[0];
  const float* ihw  = (const float*)d_in[1];
  const float* ihb  = (const float*)d_in[2];
  const float* hhw  = (const float*)d_in[3];
  const float* ln1w = (const float*)d_in[4];
  const float* ln1b = (const float*)d_in[5];
  const float* hnw  = (const float*)d_in[6];
  const float* hnb  = (const float*)d_in[7];
  const float* ln2w = (const float*)d_in[8];
  const float* ln2b = (const float*)d_in[9];
  const float* ffw1 = (const float*)d_in[10];
  const float* ffb1 = (const float*)d_in[11];
  const float* ffw2 = (const float*)d_in[12];
  const float* ffb2 = (const float*)d_in[13];

  float* ws    = (float*)d_ws;
  float* r0    = ws;
  float* state = ws + 8388608;
  float* mu1   = ws + 8421376;
  float* rs1   = ws + 8437760;
  float* mu2   = ws + 8454144;
  float* rs2   = ws + 8470528;
  short* w1b   = (short*)(ws + 8486912);
  short* w2b   = (short*)(ws + 10584064);
  h2f*   hh2   = (h2f*)(ws + 11632640);
  short* xb    = (short*)(ws + 11665408);
  short* ihwb  = (short*)(ws + 12713984);
  short* gb    = (short*)r0;
  short* zb    = (short*)(ws + 4194304);
  float* out   = (float*)d_out;

  cvt_w<<<dim3(4096 / 64, 1024 / 64), 256, 0, stream>>>(ffw1, w1b, 1024, 4096);
  cvt_w<<<dim3(1024 / 64, 2048 / 64), 256, 0, stream>>>(ffw2, w2b, 2048, 1024);
  for (int h = 0; h < NHEAD; ++h)
    cvt_w<<<dim3(8, 2), 256, 0, stream>>>(ihw + (size_t)h * 65536,
                                          ihwb + (size_t)h * 8 * 8192, 128, 512);
  cvt_hh<<<128, 256, 0, stream>>>(hhw, hh2);
  ln_stats_kernel<<<NROWS, 256, 0, stream>>>(x, mu1, rs1);
  for (int cidx = 0; cidx < SEQ / CHUNK_L; ++cidx) {
    const int l0 = cidx * CHUNK_L;
    cvt_x<<<CHUNK_L * BATCH, 256, 0, stream>>>(x, mu1, rs1, ln1w, ln1b, xb, l0);
    proj_mfma<<<dim3(16, 4, NHEAD), 256, 0, stream>>>(xb, ihwb, ihb, r0);
    scan_chunk<<<BATCH * NHEAD, 512, 0, stream>>>(r0, hh2, state, out, l0);
  }
  post_kernel<<<NROWS, 256, 0, stream>>>(out, x, hnw, hnb, mu2, rs2);
  for (int rc = 0; rc < NROWS / ROWCH; ++rc) {
    const int row0 = rc * ROWCH;
    cvt_z<<<ROWCH, 256, 0, stream>>>(out, mu2, rs2, ln2w, ln2b, zb, row0);
    ff1_gemm<<<dim3(ROWCH / 128, DFF / 128), 256, 0, stream>>>(zb, w1b, ffb1, gb);
    ff2_gemm<<<dim3(ROWCH / 128, D_MODEL / 128), 256, 0, stream>>>(
        gb, w2b, ffb2, out, row0);
  }
}

// Round 19
// 2030.006 us; speedup vs baseline: 1.0061x; 1.0061x over previous
//
#include <hip/hip_runtime.h>
#include <math.h>

// ---------------------------------------------------------------------------
// sLSTM block, round 19: r16 scan body (the best measured) with the staged
// pbuf pipeline deleted -- each lane loads its single per-step proj scalar
// directly into registers (16 per group, coalesced 2KB/step rows). Removes
// 1 LDS op/step + all staging issue. FFN/proj/post = r16 (unchanged).
// Workspace: same as r16 (~49.6 MB).
// ---------------------------------------------------------------------------

#define D_MODEL 1024
#define NHEAD   8
#define DPH     128
#define DFF     2048
#define BATCH   8
#define SEQ     2048
#define NROWS   (BATCH * SEQ)   // 16384
#define CHUNK_L 256             // scan steps per launch (8 launches)
#define TGRP    16              // scan steps per register-prefetch group
#define NGRP    (CHUNK_L / TGRP)
#define ROWCH   4096            // FFN rows per chunk (4 chunks)
#define LN_EPS  1e-5f

typedef __attribute__((ext_vector_type(8))) short short8;
typedef __attribute__((ext_vector_type(4))) short short4v;
typedef __attribute__((ext_vector_type(4))) float f32x4;
typedef __attribute__((ext_vector_type(2))) _Float16 h2f;
typedef __attribute__((ext_vector_type(8))) _Float16 h8f;
union H8U { h8f v; h2f p[4]; };

#if __has_builtin(__builtin_amdgcn_fdot2)
#define DOT2(a, b, c) __builtin_amdgcn_fdot2((a), (b), (c), false)
#else
__device__ __forceinline__ float DOT2(h2f a, h2f b, float c) {
  return c + (float)a.x * (float)b.x + (float)a.y * (float)b.y;
}
#endif

#if __has_builtin(__builtin_amdgcn_rcpf)
#define FRCP(x) __builtin_amdgcn_rcpf(x)
#else
#define FRCP(x) (1.0f / (x))
#endif

__device__ __forceinline__ float qxor1(float v) {
#if __has_builtin(__builtin_amdgcn_update_dpp)
  union { float f; int i; } u; u.f = v;
  u.i = __builtin_amdgcn_update_dpp(u.i, u.i, 0xB1, 0xf, 0xf, true);
  return u.f;
#else
  return __shfl_xor(v, 1, 64);
#endif
}
__device__ __forceinline__ float qxor2(float v) {
#if __has_builtin(__builtin_amdgcn_update_dpp)
  union { float f; int i; } u; u.f = v;
  u.i = __builtin_amdgcn_update_dpp(u.i, u.i, 0x4E, 0xf, 0xf, true);
  return u.f;
#else
  return __shfl_xor(v, 2, 64);
#endif
}

// async global->LDS, 16B per lane; lds_base must be WAVE-UNIFORM
__device__ __forceinline__ void gll16(const void* src, void* lds_base, int lane) {
#if __has_builtin(__builtin_amdgcn_global_load_lds)
  __builtin_amdgcn_global_load_lds(
      (const __attribute__((address_space(1))) unsigned int*)src,
      (__attribute__((address_space(3))) unsigned int*)lds_base, 16, 0, 0);
#else
  *(float4*)((char*)lds_base + lane * 16) = *(const float4*)src;
#endif
}

__device__ __forceinline__ float gelu_exact(float x) {
  return 0.5f * x * (1.0f + erff(x * 0.70710678118654752440f));
}

__device__ __forceinline__ unsigned short f2bf(float f) {
  union { float f; unsigned int u; } v; v.f = f;
  unsigned int r = v.u + 0x7fffu + ((v.u >> 16) & 1u);
  return (unsigned short)(r >> 16);
}

// tile-image offset for element (r, k) inside a [128][64] bf16 tile
__device__ __forceinline__ int img_off(int r, int k) {
  return r * 64 + ((((k >> 3) & 7) ^ (r & 7)) << 3) + (k & 7);
}

// sLSTM gate update: division-free + single-exp max-trick; returns raw h
__device__ __forceinline__ float gate_step(float iv, float fv, float zraw, float oraw,
                                           float& c, float& nrm, float& m) {
  const float zv = 1.0f - 2.0f * FRCP(__expf(2.0f * zraw) + 1.0f);
  const float ov = FRCP(1.0f + __expf(-oraw));
  const float lf = fminf(fv, 0.0f) - __logf(1.0f + __expf(-fabsf(fv)));
  const float ft = lf + m;
  const float mn = fmaxf(ft, iv);
  const float e  = __expf(fminf(ft, iv) - mn);
  const float is = (iv < ft) ? e : 1.0f;
  const float fs = (iv < ft) ? 1.0f : e;
  c = fs * c + is * zv;
  nrm = fs * nrm + is;
  m = mn;
  return ov * c * FRCP(nrm);
}

// --------------------- per-row LN stats (mu, rstd) --------------------------
__global__ __launch_bounds__(256) void ln_stats_kernel(
    const float* __restrict__ in, float* __restrict__ mu_out,
    float* __restrict__ rs_out) {
  const int row = blockIdx.x, tid = threadIdx.x;
  const float4 v = ((const float4*)(in + (size_t)row * D_MODEL))[tid];
  float s  = v.x + v.y + v.z + v.w;
  float s2 = v.x*v.x + v.y*v.y + v.z*v.z + v.w*v.w;
  #pragma unroll
  for (int m = 1; m < 64; m <<= 1) { s += __shfl_xor(s, m, 64); s2 += __shfl_xor(s2, m, 64); }
  __shared__ float sa[4], sb[4];
  if ((tid & 63) == 0) { sa[tid >> 6] = s; sb[tid >> 6] = s2; }
  __syncthreads();
  if (tid == 0) {
    const float S  = sa[0] + sa[1] + sa[2] + sa[3];
    const float S2 = sb[0] + sb[1] + sb[2] + sb[3];
    const float mu = S * (1.0f / D_MODEL);
    const float var = S2 * (1.0f / D_MODEL) - mu * mu;
    mu_out[row] = mu;
    rs_out[row] = rsqrtf(var + LN_EPS);
  }
}

// ---- weight convert: [K][N] f32 -> bf16 tile images -------------------------
__global__ __launch_bounds__(256) void cvt_w(
    const float* __restrict__ src, short* __restrict__ dst, int K, int N) {
  __shared__ float tile[64][68];
  const int n0 = blockIdx.x * 64;
  const int k0 = blockIdx.y * 64;
  const int tid = threadIdx.x;
  #pragma unroll
  for (int i = 0; i < 16; ++i) {
    const int e = i * 256 + tid;
    const int kk = e >> 6, nn = e & 63;
    tile[kk][nn] = src[(size_t)(k0 + kk) * N + n0 + nn];
  }
  __syncthreads();
  const int ktiles = K >> 6;
  #pragma unroll
  for (int i = 0; i < 2; ++i) {
    const int e = i * 256 + tid;
    const int nn = e >> 3, kc = (e & 7) * 8;
    short8 s;
    #pragma unroll
    for (int j = 0; j < 8; ++j) s[j] = (short)f2bf(tile[kc + j][nn]);
    const int n = n0 + nn;
    const size_t base = ((size_t)(n >> 7) * ktiles + (k0 >> 6)) * 8192;
    *(short8*)(dst + base + img_off(n & 127, kc)) = s;
  }
}

// ---- hh_w [128][512] f32 -> packed f16 pairs hh2[k2][512] -------------------
__global__ __launch_bounds__(256) void cvt_hh(
    const float* __restrict__ hhw, h2f* __restrict__ hh2) {
  const int idx = blockIdx.x * 256 + threadIdx.x;
  const int k2 = idx >> 9, j = idx & 511;
  h2f v;
  v.x = (_Float16)hhw[(size_t)(2 * k2) * 512 + j];
  v.y = (_Float16)hhw[(size_t)(2 * k2 + 1) * 512 + j];
  hh2[idx] = v;
}

// ------ cvt_x: LN1(x) chunk rows as bf16 tile images -------------------------
__global__ __launch_bounds__(256) void cvt_x(
    const float* __restrict__ x, const float* __restrict__ mu1,
    const float* __restrict__ rs1, const float* __restrict__ ln1w,
    const float* __restrict__ ln1b, short* __restrict__ xb, int l0) {
  const int rowm = blockIdx.x, tid = threadIdx.x;
  const int l = l0 + (rowm >> 3), b = rowm & 7;
  const int grow = b * SEQ + l;
  const float4 v = ((const float4*)(x + (size_t)grow * D_MODEL))[tid];
  const float mu = mu1[grow], rs = rs1[grow];
  const float4 w4 = ((const float4*)ln1w)[tid];
  const float4 b4 = ((const float4*)ln1b)[tid];
  short4v s;
  s[0] = (short)f2bf((v.x - mu) * rs * w4.x + b4.x);
  s[1] = (short)f2bf((v.y - mu) * rs * w4.y + b4.y);
  s[2] = (short)f2bf((v.z - mu) * rs * w4.z + b4.z);
  s[3] = (short)f2bf((v.w - mu) * rs * w4.w + b4.w);
  const int k = tid * 4;
  const int h = k >> 7, khead = k & 127;
  const size_t base = (((size_t)(rowm >> 7) * 8 + h) * 2 + (khead >> 6)) * 8192;
  *(short4v*)(xb + base + img_off(rowm & 127, khead & 63)) = s;
}

// ---------------- proj (bf16 MFMA, gll16) + bias, bank-rotated store ---------
__global__ __launch_bounds__(256) void proj_mfma(
    const short* __restrict__ xb, const short* __restrict__ ihwb,
    const float* __restrict__ ihb, float* __restrict__ proj) {
  __shared__ short As[128 * 64];
  __shared__ short Bs[128 * 64];
  const int tid = threadIdx.x;
  const int mb = blockIdx.x;
  const int qb = blockIdx.y;
  const int h  = blockIdx.z;
  const int lane = tid & 63;
  const int w = tid >> 6;
  const int wr = w >> 1, wc = w & 1;
  const short* at = xb + ((size_t)(mb * 8 + h) * 2) * 8192;
  const short* bt = ihwb + ((size_t)(h * 8 + qb * 2)) * 8192;
  f32x4 acc[4][4];
  #pragma unroll
  for (int i = 0; i < 4; ++i)
    #pragma unroll
    for (int j = 0; j < 4; ++j) acc[i][j] = (f32x4)0.0f;
  #pragma unroll
  for (int kb = 0; kb < 2; ++kb) {
    #pragma unroll
    for (int i = 0; i < 4; ++i) {
      const int off = i * 2048 + w * 512;
      gll16(at + (size_t)kb * 8192 + off + lane * 8, As + off, lane);
      gll16(bt + (size_t)kb * 8192 + off + lane * 8, Bs + off, lane);
    }
    __syncthreads();
    #pragma unroll
    for (int ks = 0; ks < 2; ++ks) {
      short8 af[4], bf[4];
      #pragma unroll
      for (int mf = 0; mf < 4; ++mf) {
        const int row = wr * 64 + mf * 16 + (lane & 15);
        const int c8 = ks * 4 + (lane >> 4);
        af[mf] = *(const short8*)&As[row * 64 + ((c8 ^ (row & 7)) << 3)];
      }
      #pragma unroll
      for (int nf = 0; nf < 4; ++nf) {
        const int row = wc * 64 + nf * 16 + (lane & 15);
        const int c8 = ks * 4 + (lane >> 4);
        bf[nf] = *(const short8*)&Bs[row * 64 + ((c8 ^ (row & 7)) << 3)];
      }
      #pragma unroll
      for (int mf = 0; mf < 4; ++mf)
        #pragma unroll
        for (int nf = 0; nf < 4; ++nf)
          acc[mf][nf] = __builtin_amdgcn_mfma_f32_16x16x32_bf16(af[mf], bf[nf], acc[mf][nf], 0, 0, 0);
    }
    __syncthreads();
  }
  #pragma unroll
  for (int nf = 0; nf < 4; ++nf) {
    const int col = wc * 64 + nf * 16 + (lane & 15);
    const float bias = ihb[h * 512 + qb * 128 + col];
    const int pos = qb * 128 + ((col + 8 * qb) & 127);
    #pragma unroll
    for (int mf = 0; mf < 4; ++mf) {
      const int rbase = mb * 128 + wr * 64 + mf * 16 + ((lane >> 4) << 2);
      #pragma unroll
      for (int rr = 0; rr < 4; ++rr)
        proj[((size_t)(rbase + rr) * NHEAD + h) * 512 + pos] = acc[mf][nf][rr] + bias;
    }
  }
}

// ------------------------------- sLSTM scan --------------------------------
// r16 step body; proj scalar delivered via per-lane register prefetch (16 per
// group, coalesced 2KB rows per step). No pbuf, no staging asm.
__global__ __launch_bounds__(512, 1) void scan_chunk(
    const float* __restrict__ proj, const h2f* __restrict__ hh2,
    float* __restrict__ state, float* __restrict__ hout, int l0) {
  const int bh = blockIdx.x, b = bh >> 3, h = bh & 7;
  const int tid = threadIdx.x;
  const int l = tid & 63, w = tid >> 6;
  const int q = l & 3, p = l >> 2;
  const int ch = 16 * w + p;
  const int pvoff = q * 128 + ((ch + 8 * q) & 127);
  __shared__ __align__(16) _Float16 h16[2][128];
  __shared__ __align__(16) float hstage[2][TGRP][128];

  h2f w2[4][16];
  #pragma unroll
  for (int j = 0; j < 4; ++j)
    #pragma unroll
    for (int kk = 0; kk < 16; ++kk)
      w2[j][kk] = hh2[(size_t)(16 * q + kk) * 512 + j * 128 + ch];

  float c, nrm, m;
  if (l0 == 0) {
    c = 0.0f; nrm = 0.0f; m = -1e30f;
    if (q == 0) h16[0][ch] = (_Float16)0.0f;
  } else {
    c   = state[bh * 128 + ch];
    nrm = state[8192  + bh * 128 + ch];
    m   = state[16384 + bh * 128 + ch];
    if (q == 0) h16[0][ch] = (_Float16)state[24576 + bh * 128 + ch];
  }

  // per-lane proj stream: one scalar per step at stride 32768 floats
  const float* prow = proj + (size_t)bh * 512 + pvoff;

  float pv[TGRP];
  #pragma unroll
  for (int t = 0; t < TGRP; ++t) pv[t] = prow[(size_t)t * 32768];
  __syncthreads();                                   // h16[0] visible

  float hv = 0.0f;
  for (int grp = 0; grp < NGRP; ++grp) {
    const int gb = grp & 1;
    // prefetch next group's proj scalars (drain at step barriers)
    float pvn[TGRP];
    if (grp + 1 < NGRP) {
      #pragma unroll
      for (int t = 0; t < TGRP; ++t)
        pvn[t] = prow[(size_t)((grp + 1) * TGRP + t) * 32768];
    }
    #pragma unroll
    for (int tl = 0; tl < TGRP; ++tl) {
      const int cur = tl & 1;
      float pa0 = 0.0f, pa1 = 0.0f, pa2 = 0.0f, pa3 = 0.0f;
      {
        const h8f* hp = (const h8f*)&h16[cur][q * 32];   // 4 x ds_read_b128
        #pragma unroll
        for (int i = 0; i < 4; ++i) {
          H8U u; u.v = hp[i];
          #pragma unroll
          for (int e = 0; e < 4; ++e) {
            const int kk = i * 4 + e;
            pa0 = DOT2(u.p[e], w2[0][kk], pa0);
            pa1 = DOT2(u.p[e], w2[1][kk], pa1);
            pa2 = DOT2(u.p[e], w2[2][kk], pa2);
            pa3 = DOT2(u.p[e], w2[3][kk], pa3);
          }
        }
      }
      // proj term from registers; lane q owns column q*128+ch
      const float pvv = pv[tl];
      pa0 += (q == 0) ? pvv : 0.0f;
      pa1 += (q == 1) ? pvv : 0.0f;
      pa2 += (q == 2) ? pvv : 0.0f;
      pa3 += (q == 3) ? pvv : 0.0f;
      // quad butterfly (VALU DPP)
      pa0 += qxor1(pa0); pa1 += qxor1(pa1); pa2 += qxor1(pa2); pa3 += qxor1(pa3);
      pa0 += qxor2(pa0); pa1 += qxor2(pa1); pa2 += qxor2(pa2); pa3 += qxor2(pa3);
      hv = gate_step(pa0, pa1, pa2, pa3, c, nrm, m);
      if (q == 0) {
        h16[cur ^ 1][ch] = (_Float16)hv;
        hstage[gb][tl][ch] = hv;
      }
      __syncthreads();                               // the one barrier per step
    }
    // coalesced h dump (hstage dbuf -> no extra barrier)
    {
      const int s = tid >> 5, c8 = (tid & 31) << 2;
      const float4 v0 = *(const float4*)&hstage[gb][s][c8];
      *(float4*)(hout + ((size_t)(b * SEQ + l0 + grp * TGRP + s)) * D_MODEL
                 + h * DPH + c8) = v0;
    }
    #pragma unroll
    for (int t = 0; t < TGRP; ++t) pv[t] = pvn[t];
  }

  if (q == 0) {
    state[bh * 128 + ch]          = c;
    state[8192  + bh * 128 + ch]  = nrm;
    state[16384 + bh * 128 + ch]  = m;
    state[24576 + bh * 128 + ch]  = hv;
  }
}

// ---------- post: y = headLN(h) + x in place on d_out ; LN2 row stats -------
__global__ __launch_bounds__(256) void post_kernel(
    float* __restrict__ yio, const float* __restrict__ x,
    const float* __restrict__ hnw, const float* __restrict__ hnb,
    float* __restrict__ mu2, float* __restrict__ rs2) {
  const int row = blockIdx.x, tid = threadIdx.x;
  const float4 hv = ((const float4*)(yio + (size_t)row * D_MODEL))[tid];
  float s  = hv.x + hv.y + hv.z + hv.w;
  float s2 = hv.x*hv.x + hv.y*hv.y + hv.z*hv.z + hv.w*hv.w;
  #pragma unroll
  for (int mm = 1; mm < 32; mm <<= 1) {
    s  += __shfl_xor(s,  mm, 32);
    s2 += __shfl_xor(s2, mm, 32);
  }
  const float mu = s * (1.0f / DPH);
  const float var = s2 * (1.0f / DPH) - mu * mu;
  const float rstd = rsqrtf(var + LN_EPS);
  const int dq = tid & 31;
  const float4 w4 = ((const float4*)hnw)[dq];
  const float4 b4 = ((const float4*)hnb)[dq];
  const float4 xv = ((const float4*)(x + (size_t)row * D_MODEL))[tid];
  float4 yv;
  yv.x = (hv.x - mu) * rstd * w4.x + b4.x + xv.x;
  yv.y = (hv.y - mu) * rstd * w4.y + b4.y + xv.y;
  yv.z = (hv.z - mu) * rstd * w4.z + b4.z + xv.z;
  yv.w = (hv.w - mu) * rstd * w4.w + b4.w + xv.w;
  ((float4*)(yio + (size_t)row * D_MODEL))[tid] = yv;
  float t1 = yv.x + yv.y + yv.z + yv.w;
  float t2 = yv.x*yv.x + yv.y*yv.y + yv.z*yv.z + yv.w*yv.w;
  #pragma unroll
  for (int mm = 1; mm < 64; mm <<= 1) {
    t1 += __shfl_xor(t1, mm, 64);
    t2 += __shfl_xor(t2, mm, 64);
  }
  __shared__ float sa[4], sb[4];
  if ((tid & 63) == 0) { sa[tid >> 6] = t1; sb[tid >> 6] = t2; }
  __syncthreads();
  if (tid == 0) {
    const float S  = sa[0] + sa[1] + sa[2] + sa[3];
    const float S2 = sb[0] + sb[1] + sb[2] + sb[3];
    const float m2 = S * (1.0f / D_MODEL);
    const float v2 = S2 * (1.0f / D_MODEL) - m2 * m2;
    mu2[row] = m2;
    rs2[row] = rsqrtf(v2 + LN_EPS);
  }
}

// ------ cvt_z: z = LN2(y) as bf16 tile images (per ROWCH chunk) -------------
__global__ __launch_bounds__(256) void cvt_z(
    const float* __restrict__ y, const float* __restrict__ mu2,
    const float* __restrict__ rs2, const float* __restrict__ ln2w,
    const float* __restrict__ ln2b, short* __restrict__ zb, int row0) {
  const int lrow = blockIdx.x, tid = threadIdx.x;
  const int grow = row0 + lrow;
  const float4 v = ((const float4*)(y + (size_t)grow * D_MODEL))[tid];
  const float mu = mu2[grow], rs = rs2[grow];
  const float4 w4 = ((const float4*)ln2w)[tid];
  const float4 b4 = ((const float4*)ln2b)[tid];
  short4v s;
  s[0] = (short)f2bf((v.x - mu) * rs * w4.x + b4.x);
  s[1] = (short)f2bf((v.y - mu) * rs * w4.y + b4.y);
  s[2] = (short)f2bf((v.z - mu) * rs * w4.z + b4.z);
  s[3] = (short)f2bf((v.w - mu) * rs * w4.w + b4.w);
  const int k = tid * 4;
  const size_t base = ((size_t)(lrow >> 7) * 16 + (k >> 6)) * 8192;
  *(short4v*)(zb + base + img_off(lrow & 127, k & 63)) = s;
}

// ------------------------------ FF1 (bf16 MFMA, gll16) ----------------------
__global__ __launch_bounds__(256) void ff1_gemm(
    const short* __restrict__ zb, const short* __restrict__ w1b,
    const float* __restrict__ b1, short* __restrict__ g) {
  __shared__ short As[128 * 64];
  __shared__ short Bs1[128 * 64];
  __shared__ short Bs2[128 * 64];
  const int tid = threadIdx.x;
  const int mb = blockIdx.x;
  const int nb = blockIdx.y;
  const int lane = tid & 63;
  const int w = tid >> 6;
  const int wr = w >> 1, wc = w & 1;
  const short* at = zb + (size_t)mb * 16 * 8192;
  const short* b1t = w1b + (size_t)nb * 16 * 8192;
  const short* b2t = w1b + (size_t)(16 + nb) * 16 * 8192;
  f32x4 acc1[4][4], acc2[4][4];
  #pragma unroll
  for (int i = 0; i < 4; ++i)
    #pragma unroll
    for (int j = 0; j < 4; ++j) { acc1[i][j] = (f32x4)0.0f; acc2[i][j] = (f32x4)0.0f; }
  for (int kb = 0; kb < 16; ++kb) {
    #pragma unroll
    for (int i = 0; i < 4; ++i) {
      const int off = i * 2048 + w * 512;
      gll16(at + (size_t)kb * 8192 + off + lane * 8, As + off, lane);
      gll16(b1t + (size_t)kb * 8192 + off + lane * 8, Bs1 + off, lane);
      gll16(b2t + (size_t)kb * 8192 + off + lane * 8, Bs2 + off, lane);
    }
    __syncthreads();
    #pragma unroll
    for (int ks = 0; ks < 2; ++ks) {
      short8 af[4], b1f[4], b2f[4];
      #pragma unroll
      for (int mf = 0; mf < 4; ++mf) {
        const int row = wr * 64 + mf * 16 + (lane & 15);
        const int c8 = ks * 4 + (lane >> 4);
        af[mf] = *(const short8*)&As[row * 64 + ((c8 ^ (row & 7)) << 3)];
      }
      #pragma unroll
      for (int nf = 0; nf < 4; ++nf) {
        const int row = wc * 64 + nf * 16 + (lane & 15);
        const int c8 = ks * 4 + (lane >> 4);
        const int off = row * 64 + ((c8 ^ (row & 7)) << 3);
        b1f[nf] = *(const short8*)&Bs1[off];
        b2f[nf] = *(const short8*)&Bs2[off];
      }
      #pragma unroll
      for (int mf = 0; mf < 4; ++mf)
        #pragma unroll
        for (int nf = 0; nf < 4; ++nf) {
          acc1[mf][nf] = __builtin_amdgcn_mfma_f32_16x16x32_bf16(af[mf], b1f[nf], acc1[mf][nf], 0, 0, 0);
          acc2[mf][nf] = __builtin_amdgcn_mfma_f32_16x16x32_bf16(af[mf], b2f[nf], acc2[mf][nf], 0, 0, 0);
        }
    }
    __syncthreads();
  }
  #pragma unroll
  for (int nf = 0; nf < 4; ++nf) {
    const int col = nb * 128 + wc * 64 + nf * 16 + (lane & 15);
    const float bx1 = b1[col], bx2 = b1[DFF + col];
    #pragma unroll
    for (int mf = 0; mf < 4; ++mf) {
      const int rloc = wr * 64 + mf * 16 + ((lane >> 4) << 2);
      #pragma unroll
      for (int rr = 0; rr < 4; ++rr) {
        const float x1 = acc1[mf][nf][rr] + bx1;
        const float x2 = acc2[mf][nf][rr] + bx2;
        const int r = rloc + rr;
        const size_t base = ((size_t)mb * 32 + (col >> 6)) * 8192;
        g[base + img_off(r, col & 63)] = (short)f2bf(x1 * gelu_exact(x2));
      }
    }
  }
}

// --------------- FF2 (bf16 MFMA, gll16) + bias + residual, in place ----------
__global__ __launch_bounds__(256) void ff2_gemm(
    const short* __restrict__ g, const short* __restrict__ w2b,
    const float* __restrict__ b2, float* __restrict__ out, int row0) {
  __shared__ short As[128 * 64];
  __shared__ short Bs[128 * 64];
  const int tid = threadIdx.x;
  const int mb = blockIdx.x;
  const int nb = blockIdx.y;
  const int lane = tid & 63;
  const int w = tid >> 6;
  const int wr = w >> 1, wc = w & 1;
  const short* at = g + (size_t)mb * 32 * 8192;
  const short* bt = w2b + (size_t)nb * 32 * 8192;
  f32x4 acc[4][4];
  #pragma unroll
  for (int i = 0; i < 4; ++i)
    #pragma unroll
    for (int j = 0; j < 4; ++j) acc[i][j] = (f32x4)0.0f;
  for (int kb = 0; kb < 32; ++kb) {
    #pragma unroll
    for (int i = 0; i < 4; ++i) {
      const int off = i * 2048 + w * 512;
      gll16(at + (size_t)kb * 8192 + off + lane * 8, As + off, lane);
      gll16(bt + (size_t)kb * 8192 + off + lane * 8, Bs + off, lane);
    }
    __syncthreads();
    #pragma unroll
    for (int ks = 0; ks < 2; ++ks) {
      short8 af[4], bf[4];
      #pragma unroll
      for (int mf = 0; mf < 4; ++mf) {
        const int row = wr * 64 + mf * 16 + (lane & 15);
        const int c8 = ks * 4 + (lane >> 4);
        af[mf] = *(const short8*)&As[row * 64 + ((c8 ^ (row & 7)) << 3)];
      }
      #pragma unroll
      for (int nf = 0; nf < 4; ++nf) {
        const int row = wc * 64 + nf * 16 + (lane & 15);
        const int c8 = ks * 4 + (lane >> 4);
        bf[nf] = *(const short8*)&Bs[row * 64 + ((c8 ^ (row & 7)) << 3)];
      }
      #pragma unroll
      for (int mf = 0; mf < 4; ++mf)
        #pragma unroll
        for (int nf = 0; nf < 4; ++nf)
          acc[mf][nf] = __builtin_amdgcn_mfma_f32_16x16x32_bf16(af[mf], bf[nf], acc[mf][nf], 0, 0, 0);
    }
    __syncthreads();
  }
  #pragma unroll
  for (int nf = 0; nf < 4; ++nf) {
    const int col = nb * 128 + wc * 64 + nf * 16 + (lane & 15);
    const float bias = b2[col];
    #pragma unroll
    for (int mf = 0; mf < 4; ++mf) {
      const int rbase = row0 + mb * 128 + wr * 64 + mf * 16 + ((lane >> 4) << 2);
      #pragma unroll
      for (int rr = 0; rr < 4; ++rr) {
        float* p = out + (size_t)(rbase + rr) * D_MODEL + col;
        *p = acc[mf][nf][rr] + bias + *p;
      }
    }
  }
}

// ------------------------------- launcher -----------------------------------
extern "C" void kernel_launch(void* const* d_in, const int* in_sizes, int n_in,
                              void* d_out, int out_size, void* d_ws, size_t ws_size,
                              hipStream_t stream) {
  const float* x    = (const float*)d_in[0];
  const float* ihw  = (const float*)d_in[1];
  const float* ihb  = (const float*)d_in[2];
  const float* hhw  = (const float*)d_in[3];
  const float* ln1w = (const float*)d_in[4];
  const float* ln1b = (const float*)d_in[5];
  const float* hnw  = (const float*)d_in[6];
  const float* hnb  = (const float*)d_in[7];
  const float* ln2w = (const float*)d_in[8];
  const float* ln2b = (const float*)d_in[9];
  const float* ffw1 = (const float*)d_in[10];
  const float* ffb1 = (const float*)d_in[11];
  const float* ffw2 = (const float*)d_in[12];
  const float* ffb2 = (const float*)d_in[13];

  float* ws    = (float*)d_ws;
  float* r0    = ws;
  float* state = ws + 8388608;
  float* mu1   = ws + 8421376;
  float* rs1   = ws + 8437760;
  float* mu2   = ws + 8454144;
  float* rs2   = ws + 8470528;
  short* w1b   = (short*)(ws + 8486912);
  short* w2b   = (short*)(ws + 10584064);
  h2f*   hh2   = (h2f*)(ws + 11632640);
  short* xb    = (short*)(ws + 11665408);
  short* ihwb  = (short*)(ws + 12713984);
  short* gb    = (short*)r0;
  short* zb    = (short*)(ws + 4194304);
  float* out   = (float*)d_out;

  cvt_w<<<dim3(4096 / 64, 1024 / 64), 256, 0, stream>>>(ffw1, w1b, 1024, 4096);
  cvt_w<<<dim3(1024 / 64, 2048 / 64), 256, 0, stream>>>(ffw2, w2b, 2048, 1024);
  for (int h = 0; h < NHEAD; ++h)
    cvt_w<<<dim3(8, 2), 256, 0, stream>>>(ihw + (size_t)h * 65536,
                                          ihwb + (size_t)h * 8 * 8192, 128, 512);
  cvt_hh<<<128, 256, 0, stream>>>(hhw, hh2);
  ln_stats_kernel<<<NROWS, 256, 0, stream>>>(x, mu1, rs1);
  for (int cidx = 0; cidx < SEQ / CHUNK_L; ++cidx) {
    const int l0 = cidx * CHUNK_L;
    cvt_x<<<CHUNK_L * BATCH, 256, 0, stream>>>(x, mu1, rs1, ln1w, ln1b, xb, l0);
    proj_mfma<<<dim3(16, 4, NHEAD), 256, 0, stream>>>(xb, ihwb, ihb, r0);
    scan_chunk<<<BATCH * NHEAD, 512, 0, stream>>>(r0, hh2, state, out, l0);
  }
  post_kernel<<<NROWS, 256, 0, stream>>>(out, x, hnw, hnb, mu2, rs2);
  for (int rc = 0; rc < NROWS / ROWCH; ++rc) {
    const int row0 = rc * ROWCH;
    cvt_z<<<ROWCH, 256, 0, stream>>>(out, mu2, rs2, ln2w, ln2b, zb, row0);
    ff1_gemm<<<dim3(ROWCH / 128, DFF / 128), 256, 0, stream>>>(zb, w1b, ffb1, gb);
    ff2_gemm<<<dim3(ROWCH / 128, D_MODEL / 128), 256, 0, stream>>>(
        gb, w2b, ffb2, out, row0);
  }
}